// Round 1
// baseline (201.195 us; speedup 1.0000x reference)
//
#include <hip/hip_runtime.h>
#include <hip/hip_fp16.h>

#define TOKENS 8192
#define IN_F   4096
#define OUT_F  4096

typedef __attribute__((ext_vector_type(4))) int i32x4;

// ---------------- pack int32 -> int8 ----------------
__global__ void pack_i8_kernel(const int4* __restrict__ src, int4* __restrict__ dst, int n16) {
    int stride = gridDim.x * blockDim.x;
    for (int i = blockIdx.x * blockDim.x + threadIdx.x; i < n16; i += stride) {
        int4 a = src[4 * i + 0];
        int4 b = src[4 * i + 1];
        int4 c = src[4 * i + 2];
        int4 d = src[4 * i + 3];
        int4 o;
        o.x = (int)((a.x & 0xffu) | ((a.y & 0xffu) << 8) | ((a.z & 0xffu) << 16) | ((a.w & 0xffu) << 24));
        o.y = (int)((b.x & 0xffu) | ((b.y & 0xffu) << 8) | ((b.z & 0xffu) << 16) | ((b.w & 0xffu) << 24));
        o.z = (int)((c.x & 0xffu) | ((c.y & 0xffu) << 8) | ((c.z & 0xffu) << 16) | ((c.w & 0xffu) << 24));
        o.w = (int)((d.x & 0xffu) | ((d.y & 0xffu) << 8) | ((d.z & 0xffu) << 16) | ((d.w & 0xffu) << 24));
        dst[i] = o;
    }
}

// ---------------- bias echo (second tuple output) ----------------
__global__ void bias_echo_kernel(const float* __restrict__ bias, float* __restrict__ out_tail) {
    int i = blockIdx.x * blockDim.x + threadIdx.x;
    if (i < OUT_F) out_tail[i] = bias[i];
}

// ---------------- int8 GEMM, 128x128 tile, BK=128, 4 waves ----------------
__global__ __launch_bounds__(256, 2) void gemm_i8_kernel(
    const char* __restrict__ A,      // packed x  [TOKENS][IN_F] int8
    const char* __restrict__ B,      // packed w  [OUT_F][IN_F] int8 (B^T layout)
    const float* __restrict__ scale, // [OUT_F]
    const float* __restrict__ bias,  // [OUT_F]
    float* __restrict__ out)         // [TOKENS][OUT_F] fp16-valued fp32
{
    __shared__ char lds[2][2][16384]; // [buf][A/B][128 rows x 128 bytes]

    const int tid  = threadIdx.x;
    const int wid  = tid >> 6;
    const int lane = tid & 63;

    // XCD-aware bijective swizzle (nwg = 2048, divisible by 8)
    const int nwg = gridDim.x;
    const int bid = blockIdx.x;
    const int swz = (bid & 7) * (nwg >> 3) + (bid >> 3);
    const int tm = swz >> 5;   // 64 M-tiles
    const int tn = swz & 31;   // 32 N-tiles

    const char* ag = A + (size_t)(tm * 128) * IN_F;
    const char* bg = B + (size_t)(tn * 128) * IN_F;

    // staging geometry: each global_load_lds issue = 1024B = 8 rows of 128B
    // LDS dest is linear; SOURCE chunk is inverse-swizzled so a swizzled READ works.
    const int srow   = lane >> 3;              // row within 8-row group (== r&7)
    const int schunk = (lane & 7) ^ srow;      // source 16B-chunk

    i32x4 acc[4][4];
#pragma unroll
    for (int m = 0; m < 4; ++m)
#pragma unroll
        for (int n = 0; n < 4; ++n)
            acc[m][n] = (i32x4){0, 0, 0, 0};

#define STAGE(buf, kt)                                                                     \
    do {                                                                                   \
        const char* abase = ag + (kt) * 128;                                               \
        const char* bbase = bg + (kt) * 128;                                               \
        _Pragma("unroll")                                                                  \
        for (int j = 0; j < 4; ++j) {                                                      \
            int q = wid * 4 + j;                                                           \
            size_t go = (size_t)(q * 8 + srow) * IN_F + schunk * 16;                       \
            __builtin_amdgcn_global_load_lds(                                              \
                (const __attribute__((address_space(1))) void*)(abase + go),               \
                (__attribute__((address_space(3))) void*)(&lds[buf][0][q * 1024]),         \
                16, 0, 0);                                                                 \
            __builtin_amdgcn_global_load_lds(                                              \
                (const __attribute__((address_space(1))) void*)(bbase + go),               \
                (__attribute__((address_space(3))) void*)(&lds[buf][1][q * 1024]),         \
                16, 0, 0);                                                                 \
        }                                                                                  \
    } while (0)

    const int rA  = ((wid >> 1) * 64 + (lane & 15)) * 128; // byte row base in A tile
    const int rB  = ((wid & 1) * 64 + (lane & 15)) * 128;  // byte row base in B tile
    const int sw0 = ((lane >> 4) ^ (lane & 7)) << 4;       // swizzled chunk for kk=0

#define COMPUTE(buf)                                                                       \
    do {                                                                                   \
        const char* al = &lds[buf][0][0];                                                  \
        const char* bl = &lds[buf][1][0];                                                  \
        i32x4 afr[2][4], bfr[2][4];                                                        \
        _Pragma("unroll")                                                                  \
        for (int kk = 0; kk < 2; ++kk) {                                                   \
            const int sw = sw0 ^ (kk << 6);                                                \
            _Pragma("unroll")                                                              \
            for (int m = 0; m < 4; ++m)                                                    \
                afr[kk][m] = *(const i32x4*)(al + rA + m * 2048 + sw);                     \
            _Pragma("unroll")                                                              \
            for (int n = 0; n < 4; ++n)                                                    \
                bfr[kk][n] = *(const i32x4*)(bl + rB + n * 2048 + sw);                     \
        }                                                                                  \
        _Pragma("unroll")                                                                  \
        for (int kk = 0; kk < 2; ++kk)                                                     \
            _Pragma("unroll")                                                              \
            for (int m = 0; m < 4; ++m)                                                    \
                _Pragma("unroll")                                                          \
                for (int n = 0; n < 4; ++n)                                                \
                    acc[m][n] = __builtin_amdgcn_mfma_i32_16x16x64_i8(                     \
                        afr[kk][m], bfr[kk][n], acc[m][n], 0, 0, 0);                       \
    } while (0)

    STAGE(0, 0);
    __syncthreads();

    int cur = 0;
    const int NKT = IN_F / 128; // 32
    for (int kt = 0; kt < NKT; ++kt) {
        if (kt < NKT - 1) {
            if (cur == 0) STAGE(1, kt + 1); else STAGE(0, kt + 1);
        }
        if (cur == 0) COMPUTE(0); else COMPUTE(1);
        __syncthreads(); // compiler drains vmcnt(0)+lgkmcnt(0) before s_barrier
        cur ^= 1;
    }

    // ---------------- epilogue: dequant + bias, fp16 round, store fp32 ----------------
    const int fbase = tn * 128 + (wid & 1) * 64 + (lane & 15);
    const int tbase = tm * 128 + (wid >> 1) * 64 + ((lane >> 4) << 2);
    float sc[4], bi[4];
#pragma unroll
    for (int n = 0; n < 4; ++n) {
        sc[n] = scale[fbase + n * 16];
        bi[n] = bias[fbase + n * 16];
    }
#pragma unroll
    for (int m = 0; m < 4; ++m)
#pragma unroll
        for (int n = 0; n < 4; ++n)
#pragma unroll
            for (int r = 0; r < 4; ++r) {
                int t = tbase + m * 16 + r;
                float v = (float)acc[m][n][r] * sc[n] + bi[n];
                out[(size_t)t * OUT_F + fbase + n * 16] = (float)__float2half_rn(v);
            }
#undef STAGE
#undef COMPUTE
}

extern "C" void kernel_launch(void* const* d_in, const int* in_sizes, int n_in,
                              void* d_out, int out_size, void* d_ws, size_t ws_size,
                              hipStream_t stream) {
    const int*   x_i32 = (const int*)d_in[0];
    const int*   w_i32 = (const int*)d_in[1];
    const float* scale = (const float*)d_in[2];
    const float* bias  = (const float*)d_in[3];
    float*       out   = (float*)d_out;

    char* xp = (char*)d_ws;                       // 32 MB packed x
    char* wp = xp + (size_t)TOKENS * IN_F;        // 16 MB packed weight

    pack_i8_kernel<<<2048, 256, 0, stream>>>((const int4*)x_i32, (int4*)xp, TOKENS * IN_F / 16);
    pack_i8_kernel<<<1024, 256, 0, stream>>>((const int4*)w_i32, (int4*)wp, OUT_F * IN_F / 16);

    gemm_i8_kernel<<<(TOKENS / 128) * (OUT_F / 128), 256, 0, stream>>>(xp, wp, scale, bias, out);

    bias_echo_kernel<<<(OUT_F + 255) / 256, 256, 0, stream>>>(bias, out + (size_t)TOKENS * OUT_F);
}

// Round 2
// 191.965 us; speedup vs baseline: 1.0481x; 1.0481x over previous
//
#include <hip/hip_runtime.h>
#include <hip/hip_fp16.h>

#define TOKENS 8192
#define IN_F   4096
#define OUT_F  4096
#define NKT    (IN_F / 64)   // 64 K-tiles of 64 bytes

typedef __attribute__((ext_vector_type(4))) int i32x4;

// ---------------- prep: pack int32->int8 (x and w) + bias echo ----------------
__global__ void prep_kernel(const int4* __restrict__ xs, const int4* __restrict__ ws,
                            const float* __restrict__ bias,
                            int4* __restrict__ xp, int4* __restrict__ wp,
                            float* __restrict__ out_tail) {
    const int NX = TOKENS * IN_F / 16;
    const int NW = OUT_F * IN_F / 16;
    const int gid = blockIdx.x * blockDim.x + threadIdx.x;
    const int stride = gridDim.x * blockDim.x;
    for (int i = gid; i < NX + NW; i += stride) {
        const int4* s; int4* d; int j;
        if (i < NX) { s = xs; d = xp; j = i; }
        else        { s = ws; d = wp; j = i - NX; }
        int4 a = s[4 * j + 0];
        int4 b = s[4 * j + 1];
        int4 c = s[4 * j + 2];
        int4 e = s[4 * j + 3];
        int4 o;
        o.x = (int)((a.x & 0xffu) | ((a.y & 0xffu) << 8) | ((a.z & 0xffu) << 16) | ((a.w & 0xffu) << 24));
        o.y = (int)((b.x & 0xffu) | ((b.y & 0xffu) << 8) | ((b.z & 0xffu) << 16) | ((b.w & 0xffu) << 24));
        o.z = (int)((c.x & 0xffu) | ((c.y & 0xffu) << 8) | ((c.z & 0xffu) << 16) | ((c.w & 0xffu) << 24));
        o.w = (int)((e.x & 0xffu) | ((e.y & 0xffu) << 8) | ((e.z & 0xffu) << 16) | ((e.w & 0xffu) << 24));
        d[j] = o;
    }
    if (gid < OUT_F) out_tail[gid] = bias[gid];
}

// ---------------- int8 GEMM: 256x256 tile, BK=64B, 4-buf ring, counted vmcnt ----------------
__global__ __launch_bounds__(512, 2) void gemm_i8_kernel(
    const char* __restrict__ A,      // packed x  [TOKENS][IN_F] int8
    const char* __restrict__ B,      // packed w  [OUT_F][IN_F] int8 (B^T layout)
    const float* __restrict__ scale, // [OUT_F]
    const float* __restrict__ bias,  // [OUT_F]
    float* __restrict__ out)         // [TOKENS][OUT_F] fp16-valued fp32
{
    __shared__ char lds[4][2][16384]; // [ring buf][A/B][256 rows x 64 B]

    const int tid  = threadIdx.x;
    const int wid  = tid >> 6;
    const int lane = tid & 63;
    const int wm   = wid >> 2;   // 0..1  (M half)
    const int wn   = wid & 3;    // 0..3  (N quarter)

    // XCD-aware bijective swizzle (nwg = 512, divisible by 8)
    const int nwg = gridDim.x;
    const int bid = blockIdx.x;
    const int swz = (bid & 7) * (nwg >> 3) + (bid >> 3);
    const int tm = swz >> 4;   // 32 M-tiles
    const int tn = swz & 15;   // 16 N-tiles

    const char* ag = A + (size_t)(tm * 256) * IN_F;
    const char* bg = B + (size_t)(tn * 256) * IN_F;

    // Staging: one global_load_lds issue = 512 thr x 16B = 128 rows x 64B.
    // Thread covers row = j*128 + wid*16 + (lane>>2), chunk = lane&3 (linear LDS dest).
    // Source chunk is inverse-XOR-swizzled so swizzled reads see global[row][c] at
    // LDS[row][c ^ (row&3)]  (row&3 == (lane>>2)&3, thread-constant).
    const int srow16 = wid * 16 + (lane >> 2);
    const int schunk = ((lane & 3) ^ ((lane >> 2) & 3)) << 4;
    const int ldst   = wid * 1024 + lane * 16;

    i32x4 acc[8][4];
#pragma unroll
    for (int m = 0; m < 8; ++m)
#pragma unroll
        for (int n = 0; n < 4; ++n)
            acc[m][n] = (i32x4){0, 0, 0, 0};

#define STAGE(r, t)                                                                        \
    do {                                                                                   \
        _Pragma("unroll")                                                                  \
        for (int j = 0; j < 2; ++j) {                                                      \
            size_t go = (size_t)(j * 128 + srow16) * IN_F + (size_t)(t) * 64 + schunk;     \
            __builtin_amdgcn_global_load_lds(                                              \
                (const __attribute__((address_space(1))) void*)(ag + go),                  \
                (__attribute__((address_space(3))) void*)(&lds[r][0][j * 8192 + ldst]),    \
                16, 0, 0);                                                                 \
            __builtin_amdgcn_global_load_lds(                                              \
                (const __attribute__((address_space(1))) void*)(bg + go),                  \
                (__attribute__((address_space(3))) void*)(&lds[r][1][j * 8192 + ldst]),    \
                16, 0, 0);                                                                 \
        }                                                                                  \
    } while (0)

    // Fragment read addressing (16x16x64 i8, layout verified in round 1):
    // lane holds row (lane&15), k-group (lane>>4) of 16 bytes. Swizzled chunk = kg ^ (row&3).
    const int kg   = lane >> 4;
    const int sxa  = lane & 3;                                   // row&3 for frag rows
    const int aoff = (wm * 128 + (lane & 15)) * 64 + ((kg ^ sxa) << 4); // + m*1024
    const int boff = (wn * 64  + (lane & 15)) * 64 + ((kg ^ sxa) << 4); // + n*1024

#define STEP(t, VM, DOSTAGE)                                                               \
    do {                                                                                   \
        asm volatile("s_waitcnt vmcnt(" #VM ")" ::: "memory");                             \
        __builtin_amdgcn_s_barrier();                                                      \
        asm volatile("" ::: "memory");                                                     \
        __builtin_amdgcn_sched_barrier(0);                                                 \
        if (DOSTAGE) STAGE(((t) + 3) & 3, (t) + 3);                                        \
        const char* al = &lds[(t) & 3][0][0];                                              \
        const char* bl = &lds[(t) & 3][1][0];                                              \
        i32x4 afr[8], bfr[4];                                                              \
        _Pragma("unroll")                                                                  \
        for (int m = 0; m < 8; ++m) afr[m] = *(const i32x4*)(al + aoff + m * 1024);        \
        _Pragma("unroll")                                                                  \
        for (int n = 0; n < 4; ++n) bfr[n] = *(const i32x4*)(bl + boff + n * 1024);        \
        __builtin_amdgcn_s_setprio(1);                                                     \
        _Pragma("unroll")                                                                  \
        for (int m = 0; m < 8; ++m)                                                        \
            _Pragma("unroll")                                                              \
            for (int n = 0; n < 4; ++n)                                                    \
                acc[m][n] = __builtin_amdgcn_mfma_i32_16x16x64_i8(                         \
                    afr[m], bfr[n], acc[m][n], 0, 0, 0);                                   \
        __builtin_amdgcn_s_setprio(0);                                                     \
    } while (0)

    // Prologue: 3 K-tiles in flight (12 loads).
    STAGE(0, 0);
    STAGE(1, 1);
    STAGE(2, 2);

    // Steady state: wait tile t (all but 8 newest loads = tiles t+1,t+2), stage t+3.
    for (int t = 0; t < NKT - 3; ++t) STEP(t, 8, 1);
    STEP(NKT - 3, 8, 0);
    STEP(NKT - 2, 4, 0);
    STEP(NKT - 1, 0, 0);

    // ---------------- epilogue: dequant + bias, fp16 round, store fp32 ----------------
    const int col  = tn * 256 + wn * 64 + (lane & 15);
    const int row0 = tm * 256 + wm * 128 + ((lane >> 4) << 2);
    float sc[4], bi[4];
#pragma unroll
    for (int n = 0; n < 4; ++n) {
        sc[n] = scale[col + n * 16];
        bi[n] = bias[col + n * 16];
    }
#pragma unroll
    for (int m = 0; m < 8; ++m)
#pragma unroll
        for (int n = 0; n < 4; ++n)
#pragma unroll
            for (int r = 0; r < 4; ++r) {
                float v = (float)acc[m][n][r] * sc[n] + bi[n];
                out[(size_t)(row0 + m * 16 + r) * OUT_F + col + n * 16] =
                    (float)__float2half_rn(v);
            }
#undef STAGE
#undef STEP
}

extern "C" void kernel_launch(void* const* d_in, const int* in_sizes, int n_in,
                              void* d_out, int out_size, void* d_ws, size_t ws_size,
                              hipStream_t stream) {
    const int*   x_i32 = (const int*)d_in[0];
    const int*   w_i32 = (const int*)d_in[1];
    const float* scale = (const float*)d_in[2];
    const float* bias  = (const float*)d_in[3];
    float*       out   = (float*)d_out;

    char* xp = (char*)d_ws;                   // 32 MB packed x
    char* wp = xp + (size_t)TOKENS * IN_F;    // 16 MB packed weight

    prep_kernel<<<3072, 256, 0, stream>>>((const int4*)x_i32, (const int4*)w_i32, bias,
                                          (int4*)xp, (int4*)wp, out + (size_t)TOKENS * OUT_F);

    gemm_i8_kernel<<<(TOKENS / 256) * (OUT_F / 256), 512, 0, stream>>>(xp, wp, scale, bias, out);
}